// Round 7
// baseline (54.702 us; speedup 1.0000x reference)
//
#include <hip/hip_runtime.h>
#include <hip/hip_bf16.h>
#include <cmath>

namespace {

typedef __attribute__((ext_vector_type(8))) short bf16x8;
typedef __attribute__((ext_vector_type(4))) float f32x4;

constexpr float kNegInf = -1000000000.0f;
constexpr float kSlope  = 0.2f;
constexpr float kLog2e  = 1.44269504088896340736f;

__device__ __forceinline__ unsigned short f2bf(float x) {
  unsigned int u = __float_as_uint(x);
  u = (u + 0x7FFFu + ((u >> 16) & 1u)) >> 16;  // RNE
  return (unsigned short)u;
}
// packed pair: returns (bf16(b)<<16) | bf16(a)  via v_cvt_pk_bf16_f32
__device__ __forceinline__ unsigned int f2bf2(float a, float b) {
  __hip_bfloat162 t = __float22bfloat162_rn(float2{a, b});
  union { __hip_bfloat162 h; unsigned int u; } c;
  c.h = t;
  return c.u;
}
__device__ __forceinline__ float exp2_hw(float x) {
#if __has_builtin(__builtin_amdgcn_exp2f)
  return __builtin_amdgcn_exp2f(x);
#else
  float r;
  asm("v_exp_f32 %0, %1\n\ts_nop 1" : "=v"(r) : "v"(x));
  return r;
#endif
}

// ---------------- ws layout ----------------
// [0)        ushort wf[18432]     [W | wa1 wa2] B-frag order, bf16 (wa log2e-scaled)
// [36864)    uint   adjp[512]
// [38912)    float  wa1[128], [39424) wa2[128], [39936) ba[2]
// --- big path only ---
// [40960)    float  wsF [BS][256]      f1 | f2 per bs           (1 MB)
// [1089536)  ushort wsWh[BS][16384]    Wh in B-frag order       (32 MB)
constexpr size_t kOffF  = 40960;
constexpr size_t kOffWh = 1089536;

__global__ void prep1(const float* __restrict__ Ww, const float* __restrict__ Wb,
                      const float* __restrict__ a1v, const float* __restrict__ a2v,
                      float* __restrict__ wa1, float* __restrict__ wa2,
                      float* __restrict__ ba) {
  const int k = threadIdx.x;
  if (k < 128) {
    float s1 = 0.f, s2 = 0.f;
    for (int g = 0; g < 128; ++g) {
      const float w = Ww[k * 128 + g];
      s1 = fmaf(w, a1v[g], s1);
      s2 = fmaf(w, a2v[g], s2);
    }
    wa1[k] = s1 * kLog2e;
    wa2[k] = s2 * kLog2e;
  }
  if (k == 128) {
    float s1 = 0.f, s2 = 0.f;
    for (int g = 0; g < 128; ++g) {
      s1 = fmaf(Wb[g], a1v[g], s1);
      s2 = fmaf(Wb[g], a2v[g], s2);
    }
    ba[0] = s1 * kLog2e;
    ba[1] = s2 * kLog2e;
  }
}

__global__ void prep2(const float* __restrict__ Ww, const int* __restrict__ adj,
                      const float* __restrict__ wa1, const float* __restrict__ wa2,
                      unsigned short* __restrict__ wf, unsigned int* __restrict__ adjp) {
  const int tid = blockIdx.x * 256 + threadIdx.x;
  if (tid < 18432) {
    // frag order: wf[g][kc][lane][j] = B[k = kc*32 + (lane>>4)*8 + j][col = g*16 + (lane&15)]
    const int j = tid & 7, l = (tid >> 3) & 63, kc = (tid >> 9) & 3, g = tid >> 11;
    const int k = kc * 32 + ((l >> 4) << 3) + j;
    const int c = l & 15;
    float x;
    if (g < 8) x = Ww[k * 128 + g * 16 + c];
    else       x = (c == 0) ? wa1[k] : (c == 1) ? wa2[k] : 0.f;
    wf[tid] = f2bf(x);
  }
  if (tid < 512) {
    const int row = tid >> 2, wd = tid & 3;
    const int* ap = adj + row * 128 + wd * 32;
    unsigned int bits = 0u;
#pragma unroll
    for (int b = 0; b < 32; ++b) bits |= (ap[b] != 0 ? (1u << b) : 0u);
    adjp[tid] = bits;
  }
}

// ============ big path: K1 — streaming GEMM, no LDS, no barriers ============
__global__ __launch_bounds__(256, 4) void gat_gemm1(
    const float* __restrict__ h, const float* __restrict__ Wb,
    const unsigned short* __restrict__ wf, const float* __restrict__ ba,
    unsigned short* __restrict__ wsWh, float* __restrict__ wsF) {
  const int t = threadIdx.x, lane = t & 63, w = t >> 6;
  const int lr = lane & 15, lg = lane >> 4;
  const int bs = blockIdx.x;
  const float* hblk = h + (size_t)bs * 16384;
  const int R0 = w * 32;

  bf16x8 ha[2][4];
#pragma unroll
  for (int rt = 0; rt < 2; ++rt)
#pragma unroll
    for (int kc = 0; kc < 4; ++kc) {
      const float* p = hblk + (R0 + rt * 16 + lr) * 128 + kc * 32 + lg * 8;
      f32x4 v0 = *(const f32x4*)p;
      f32x4 v1 = *(const f32x4*)(p + 4);
      union { bf16x8 v; unsigned int u[4]; } pk;
      pk.u[0] = f2bf2(v0[0], v0[1]);
      pk.u[1] = f2bf2(v0[2], v0[3]);
      pk.u[2] = f2bf2(v1[0], v1[1]);
      pk.u[3] = f2bf2(v1[2], v1[3]);
      ha[rt][kc] = pk.v;
    }

  f32x4 acc[2][9];
#pragma unroll
  for (int rt = 0; rt < 2; ++rt)
#pragma unroll
    for (int g = 0; g < 9; ++g) acc[rt][g] = (f32x4){0.f, 0.f, 0.f, 0.f};

#pragma unroll
  for (int g = 0; g < 9; ++g)
#pragma unroll
    for (int kc = 0; kc < 4; ++kc) {
      const bf16x8 bh = *(const bf16x8*)(wf + ((g * 4 + kc) * 64 + lane) * 8);
      acc[0][g] = __builtin_amdgcn_mfma_f32_16x16x32_bf16(ha[0][kc], bh, acc[0][g], 0, 0, 0);
      acc[1][g] = __builtin_amdgcn_mfma_f32_16x16x32_bf16(ha[1][kc], bh, acc[1][g], 0, 0, 0);
    }

  float wbc[8];
#pragma unroll
  for (int g = 0; g < 8; ++g) wbc[g] = Wb[g * 16 + lr];
  const float ba1 = ba[0], ba2 = ba[1];
  unsigned short* whb = wsWh + (size_t)bs * 16384;
  float* fb = wsF + bs * 256;

#pragma unroll
  for (int rt = 0; rt < 2; ++rt) {
#pragma unroll
    for (int r = 0; r < 4; ++r) {
      // C/D layout: row = R0 + rt*16 + lg*4 + r, col = g*16 + lr
#pragma unroll
      for (int g = 0; g < 8; ++g) acc[rt][g][r] += wbc[g];
      const int row = R0 + rt * 16 + lg * 4 + r;
      if (lr == 0)      fb[row]       = acc[rt][8][r] + ba1;
      else if (lr == 1) fb[128 + row] = acc[rt][8][r] + ba2;
    }
#pragma unroll
    for (int g = 0; g < 8; ++g) {
      const unsigned int plo = f2bf2(acc[rt][g][0], acc[rt][g][1]);
      const unsigned int phi = f2bf2(acc[rt][g][2], acc[rt][g][3]);
      const int lp = (2 * rt + (lg >> 1)) * 16 + lr;
      const int jb = (lg & 1) * 4;
      *(uint2*)(whb + ((g * 4 + w) * 64 + lp) * 8 + jb) = make_uint2(plo, phi);
    }
  }
}

// ============ big path: K2 — attention + matmul2, no __syncthreads ============
__global__ __launch_bounds__(256, 4) void gat_attn(
    const unsigned short* __restrict__ wsWh, const float* __restrict__ wsF,
    const unsigned int* __restrict__ adjp, const float* __restrict__ abp,
    float* __restrict__ out) {
  __shared__ float stage[4][16][132];  // per-wave store stage (33792 B)
  const int t = threadIdx.x, lane = t & 63, w = t >> 6;
  const int lr = lane & 15, lg = lane >> 4;
  const int bs = blockIdx.x;
  const float ab2 = abp[0] * kLog2e;
  const float* fb = wsF + bs * 256;
  const unsigned short* whb = wsWh + (size_t)bs * 16384;
  const int R0 = w * 32;

  // ---------------- P-build: single pass, log2 domain ----------------
  bf16x8 af[2][4];
  float s0 = 0.f, s1 = 0.f;
  const float f1i0 = fb[R0 + lr] + ab2;
  const float f1i1 = fb[R0 + 16 + lr] + ab2;
  const int rq0 = (R0 + lr) * 4, rq1 = (R0 + 16 + lr) * 4;
#pragma unroll
  for (int kc = 0; kc < 4; ++kc) {
    const f32x4 fv0 = *(const f32x4*)(fb + 128 + kc * 32 + lg * 8);
    const f32x4 fv1 = *(const f32x4*)(fb + 128 + kc * 32 + lg * 8 + 4);
    const unsigned int aw0 = adjp[rq0 + kc];
    const unsigned int aw1 = adjp[rq1 + kc];
    union { bf16x8 v; unsigned int u[4]; } pk0, pk1;
#pragma unroll
    for (int qq = 0; qq < 4; ++qq) {
      float e0[2], e1[2];
#pragma unroll
      for (int hh = 0; hh < 2; ++hh) {
        const int q = qq * 2 + hh;
        const float fj = (q < 4) ? fv0[q] : fv1[q - 4];
        const unsigned int bit = 1u << (lg * 8 + q);
        float x0 = f1i0 + fj;
        x0 = x0 >= 0.f ? x0 : kSlope * x0;
        x0 = (aw0 & bit) ? x0 : kNegInf;
        e0[hh] = exp2_hw(x0);
        float x1 = f1i1 + fj;
        x1 = x1 >= 0.f ? x1 : kSlope * x1;
        x1 = (aw1 & bit) ? x1 : kNegInf;
        e1[hh] = exp2_hw(x1);
      }
      const unsigned int u0 = f2bf2(e0[0], e0[1]);
      const unsigned int u1 = f2bf2(e1[0], e1[1]);
      pk0.u[qq] = u0;
      pk1.u[qq] = u1;
      s0 += __uint_as_float(u0 << 16) + __uint_as_float(u0 & 0xffff0000u);
      s1 += __uint_as_float(u1 << 16) + __uint_as_float(u1 & 0xffff0000u);
    }
    af[0][kc] = pk0.v;
    af[1][kc] = pk1.v;
  }
  s0 += __shfl_xor(s0, 16);
  s0 += __shfl_xor(s0, 32);
  s1 += __shfl_xor(s1, 16);
  s1 += __shfl_xor(s1, 32);
  float rs[2] = {s0, s1};

  // ---------------- matmul2: h'·l = P @ Wh  (B-frags straight from ws) ----------------
  f32x4 acc2[2][8];
#pragma unroll
  for (int rt = 0; rt < 2; ++rt)
#pragma unroll
    for (int g = 0; g < 8; ++g) acc2[rt][g] = (f32x4){0.f, 0.f, 0.f, 0.f};

#pragma unroll
  for (int g = 0; g < 8; ++g)
#pragma unroll
    for (int kc = 0; kc < 4; ++kc) {
      const bf16x8 bw = *(const bf16x8*)(whb + ((g * 4 + kc) * 64 + lane) * 8);
      acc2[0][g] = __builtin_amdgcn_mfma_f32_16x16x32_bf16(af[0][kc], bw, acc2[0][g], 0, 0, 0);
      acc2[1][g] = __builtin_amdgcn_mfma_f32_16x16x32_bf16(af[1][kc], bw, acc2[1][g], 0, 0, 0);
    }

  // ---------------- normalize + elu + wave-local staged store ----------------
  float* oblk = out + (size_t)bs * 16384;
#pragma unroll
  for (int rt = 0; rt < 2; ++rt) {
    float inv[4];
#pragma unroll
    for (int r = 0; r < 4; ++r) {
      const float lsum = __shfl(rs[rt], (lane & 48) | (lg * 4 + r));
      inv[r] = __builtin_amdgcn_rcpf(lsum);
    }
#pragma unroll
    for (int r = 0; r < 4; ++r)
#pragma unroll
      for (int g = 0; g < 8; ++g) {
        float v = acc2[rt][g][r] * inv[r];
        v = v > 0.f ? v : __expf(v) - 1.0f;
        stage[w][lg * 4 + r][g * 16 + lr] = v;
      }
    // wave-local RAW: DS in-order per wave, compiler inserts lgkmcnt
#pragma unroll
    for (int sstep = 0; sstep < 8; ++sstep) {
      const int row16 = ((sstep & 1) << 3) + (lane >> 3);
      const int cd    = ((sstep >> 1) << 5) + ((lane & 7) << 2);
      f32x4 vv = *(const f32x4*)(&stage[w][row16][cd]);
      *(f32x4*)(oblk + (size_t)(R0 + rt * 16 + row16) * 128 + cd) = vv;
    }
  }
}

// ============ fallback: fused single kernel (R6) ============
struct SMemA {
  unsigned short Whs[8][4][64][8];
  float f1s[128];
  float f2s[128];
  unsigned int adjs[512];
};
union SMemU {
  SMemA a;
  float stage[4][16][132];
};

__global__ __launch_bounds__(256, 4) void gat_mfma(
    const float* __restrict__ h, const float* __restrict__ Wb,
    const float* __restrict__ abp, const unsigned short* __restrict__ wf,
    const unsigned int* __restrict__ adjp, const float* __restrict__ ba,
    float* __restrict__ out) {
  __shared__ SMemU smu;
  SMemA& sm = smu.a;
  const int t = threadIdx.x, lane = t & 63, w = t >> 6;
  const int lr = lane & 15, lg = lane >> 4;
  const int bs = blockIdx.x;
  const float ab2 = abp[0] * kLog2e;

  *(uint2*)(sm.adjs + t * 2) = *(const uint2*)(adjp + t * 2);

  const float* hblk = h + (size_t)bs * 16384;
  const int R0 = w * 32;

  bf16x8 ha[2][4];
#pragma unroll
  for (int rt = 0; rt < 2; ++rt)
#pragma unroll
    for (int kc = 0; kc < 4; ++kc) {
      const float* p = hblk + (R0 + rt * 16 + lr) * 128 + kc * 32 + lg * 8;
      f32x4 v0 = *(const f32x4*)p;
      f32x4 v1 = *(const f32x4*)(p + 4);
      union { bf16x8 v; unsigned int u[4]; } pk;
      pk.u[0] = f2bf2(v0[0], v0[1]);
      pk.u[1] = f2bf2(v0[2], v0[3]);
      pk.u[2] = f2bf2(v1[0], v1[1]);
      pk.u[3] = f2bf2(v1[2], v1[3]);
      ha[rt][kc] = pk.v;
    }

  f32x4 acc[2][9];
#pragma unroll
  for (int rt = 0; rt < 2; ++rt)
#pragma unroll
    for (int g = 0; g < 9; ++g) acc[rt][g] = (f32x4){0.f, 0.f, 0.f, 0.f};

#pragma unroll
  for (int g = 0; g < 9; ++g)
#pragma unroll
    for (int kc = 0; kc < 4; ++kc) {
      const bf16x8 bh = *(const bf16x8*)(wf + ((g * 4 + kc) * 64 + lane) * 8);
      acc[0][g] = __builtin_amdgcn_mfma_f32_16x16x32_bf16(ha[0][kc], bh, acc[0][g], 0, 0, 0);
      acc[1][g] = __builtin_amdgcn_mfma_f32_16x16x32_bf16(ha[1][kc], bh, acc[1][g], 0, 0, 0);
    }

  float wbc[8];
#pragma unroll
  for (int g = 0; g < 8; ++g) wbc[g] = Wb[g * 16 + lr];
  const float ba1 = ba[0], ba2 = ba[1];

#pragma unroll
  for (int rt = 0; rt < 2; ++rt) {
#pragma unroll
    for (int r = 0; r < 4; ++r) {
#pragma unroll
      for (int g = 0; g < 8; ++g) acc[rt][g][r] += wbc[g];
      const int row = R0 + rt * 16 + lg * 4 + r;
      if (lr == 0)      sm.f1s[row] = acc[rt][8][r] + ba1;
      else if (lr == 1) sm.f2s[row] = acc[rt][8][r] + ba2;
    }
#pragma unroll
    for (int g = 0; g < 8; ++g) {
      const unsigned int plo = f2bf2(acc[rt][g][0], acc[rt][g][1]);
      const unsigned int phi = f2bf2(acc[rt][g][2], acc[rt][g][3]);
      const int lp = (2 * rt + (lg >> 1)) * 16 + lr;
      const int jb = (lg & 1) * 4;
      *(uint2*)(&sm.Whs[g][w][lp][jb]) = make_uint2(plo, phi);
    }
  }
  __syncthreads();

  bf16x8 af[2][4];
  float s0 = 0.f, s1 = 0.f;
  const float f1i0 = sm.f1s[R0 + lr] + ab2;
  const float f1i1 = sm.f1s[R0 + 16 + lr] + ab2;
  const int rq0 = (R0 + lr) * 4, rq1 = (R0 + 16 + lr) * 4;
#pragma unroll
  for (int kc = 0; kc < 4; ++kc) {
    const f32x4 fv0 = *(const f32x4*)(&sm.f2s[kc * 32 + lg * 8]);
    const f32x4 fv1 = *(const f32x4*)(&sm.f2s[kc * 32 + lg * 8 + 4]);
    const unsigned int aw0 = sm.adjs[rq0 + kc];
    const unsigned int aw1 = sm.adjs[rq1 + kc];
    union { bf16x8 v; unsigned int u[4]; } pk0, pk1;
#pragma unroll
    for (int qq = 0; qq < 4; ++qq) {
      float e0[2], e1[2];
#pragma unroll
      for (int hh = 0; hh < 2; ++hh) {
        const int q = qq * 2 + hh;
        const float fj = (q < 4) ? fv0[q] : fv1[q - 4];
        const unsigned int bit = 1u << (lg * 8 + q);
        float x0 = f1i0 + fj;
        x0 = x0 >= 0.f ? x0 : kSlope * x0;
        x0 = (aw0 & bit) ? x0 : kNegInf;
        e0[hh] = exp2_hw(x0);
        float x1 = f1i1 + fj;
        x1 = x1 >= 0.f ? x1 : kSlope * x1;
        x1 = (aw1 & bit) ? x1 : kNegInf;
        e1[hh] = exp2_hw(x1);
      }
      const unsigned int u0 = f2bf2(e0[0], e0[1]);
      const unsigned int u1 = f2bf2(e1[0], e1[1]);
      pk0.u[qq] = u0;
      pk1.u[qq] = u1;
      s0 += __uint_as_float(u0 << 16) + __uint_as_float(u0 & 0xffff0000u);
      s1 += __uint_as_float(u1 << 16) + __uint_as_float(u1 & 0xffff0000u);
    }
    af[0][kc] = pk0.v;
    af[1][kc] = pk1.v;
  }
  s0 += __shfl_xor(s0, 16);
  s0 += __shfl_xor(s0, 32);
  s1 += __shfl_xor(s1, 16);
  s1 += __shfl_xor(s1, 32);
  float rs[2] = {s0, s1};

  f32x4 acc2[2][8];
#pragma unroll
  for (int rt = 0; rt < 2; ++rt)
#pragma unroll
    for (int g = 0; g < 8; ++g) acc2[rt][g] = (f32x4){0.f, 0.f, 0.f, 0.f};

#pragma unroll
  for (int g = 0; g < 8; ++g)
#pragma unroll
    for (int kc = 0; kc < 4; ++kc) {
      const bf16x8 bw = *(const bf16x8*)(&sm.Whs[g][kc][lane][0]);
      acc2[0][g] = __builtin_amdgcn_mfma_f32_16x16x32_bf16(af[0][kc], bw, acc2[0][g], 0, 0, 0);
      acc2[1][g] = __builtin_amdgcn_mfma_f32_16x16x32_bf16(af[1][kc], bw, acc2[1][g], 0, 0, 0);
    }
  __syncthreads();

  float* oblk = out + (size_t)bs * 16384;
#pragma unroll
  for (int rt = 0; rt < 2; ++rt) {
    float inv[4];
#pragma unroll
    for (int r = 0; r < 4; ++r) {
      const float lsum = __shfl(rs[rt], (lane & 48) | (lg * 4 + r));
      inv[r] = __builtin_amdgcn_rcpf(lsum);
    }
#pragma unroll
    for (int r = 0; r < 4; ++r)
#pragma unroll
      for (int g = 0; g < 8; ++g) {
        float v = acc2[rt][g][r] * inv[r];
        v = v > 0.f ? v : __expf(v) - 1.0f;
        smu.stage[w][lg * 4 + r][g * 16 + lr] = v;
      }
#pragma unroll
    for (int sstep = 0; sstep < 8; ++sstep) {
      const int row16 = ((sstep & 1) << 3) + (lane >> 3);
      const int cd    = ((sstep >> 1) << 5) + ((lane & 7) << 2);
      f32x4 vv = *(const f32x4*)(&smu.stage[w][row16][cd]);
      *(f32x4*)(oblk + (size_t)(R0 + rt * 16 + row16) * 128 + cd) = vv;
    }
  }
}

}  // namespace

extern "C" void kernel_launch(void* const* d_in, const int* in_sizes, int n_in,
                              void* d_out, int out_size, void* d_ws, size_t ws_size,
                              hipStream_t stream) {
  const float* h   = (const float*)d_in[0];
  const float* Ww  = (const float*)d_in[1];
  const float* Wb  = (const float*)d_in[2];
  const float* a1v = (const float*)d_in[3];
  const float* a2v = (const float*)d_in[4];
  const float* ab  = (const float*)d_in[5];
  const int*   adj = (const int*)d_in[6];
  float* out = (float*)d_out;

  unsigned short* wf   = (unsigned short*)d_ws;
  unsigned int*   adjp = (unsigned int*)((char*)d_ws + 36864);
  float*          wa1  = (float*)((char*)d_ws + 38912);
  float*          wa2  = (float*)((char*)d_ws + 39424);
  float*          ba   = (float*)((char*)d_ws + 39936);

  const int BS = in_sizes[0] / 16384;  // 1024
  const size_t need = kOffWh + (size_t)BS * 16384 * sizeof(unsigned short);

  hipLaunchKernelGGL(prep1, dim3(1), dim3(256), 0, stream, Ww, Wb, a1v, a2v, wa1, wa2, ba);
  hipLaunchKernelGGL(prep2, dim3(72), dim3(256), 0, stream, Ww, adj, wa1, wa2, wf, adjp);

  if (ws_size >= need) {
    float*          wsF  = (float*)((char*)d_ws + kOffF);
    unsigned short* wsWh = (unsigned short*)((char*)d_ws + kOffWh);
    hipLaunchKernelGGL(gat_gemm1, dim3(BS), dim3(256), 0, stream, h, Wb, wf, ba, wsWh, wsF);
    hipLaunchKernelGGL(gat_attn, dim3(BS), dim3(256), 0, stream, wsWh, wsF, adjp, ab, out);
  } else {
    hipLaunchKernelGGL(gat_mfma, dim3(BS), dim3(256), 0, stream, h, Wb, ab, wf, adjp, ba, out);
  }
}

// Round 8
// 51.730 us; speedup vs baseline: 1.0574x; 1.0574x over previous
//
#include <hip/hip_runtime.h>
#include <hip/hip_bf16.h>
#include <cmath>

namespace {

typedef __attribute__((ext_vector_type(8))) short bf16x8;
typedef __attribute__((ext_vector_type(4))) float f32x4;

constexpr float kNegInf = -1000000000.0f;
constexpr float kSlope  = 0.2f;
constexpr float kLog2e  = 1.44269504088896340736f;

__device__ __forceinline__ unsigned short f2bf(float x) {
  unsigned int u = __float_as_uint(x);
  u = (u + 0x7FFFu + ((u >> 16) & 1u)) >> 16;  // RNE
  return (unsigned short)u;
}
// packed pair via v_cvt_pk_bf16_f32
__device__ __forceinline__ unsigned int f2bf2(float a, float b) {
  __hip_bfloat162 t = __float22bfloat162_rn(float2{a, b});
  union { __hip_bfloat162 h; unsigned int u; } c;
  c.h = t;
  return c.u;
}
__device__ __forceinline__ float exp2_hw(float x) {
#if __has_builtin(__builtin_amdgcn_exp2f)
  return __builtin_amdgcn_exp2f(x);
#else
  float r;
  asm("v_exp_f32 %0, %1\n\ts_nop 1" : "=v"(r) : "v"(x));
  return r;
#endif
}

// ---------------- ws layout ----------------
// [0)      ushort wf[18432]   [W | wa1 wa2] B-frag order, bf16 (wa log2e-scaled)
// [36864)  uint   adjp[512]
// [38912)  float  wa1[128], [39424) wa2[128], [39936) ba[2]

__global__ void prep1(const float* __restrict__ Ww, const float* __restrict__ Wb,
                      const float* __restrict__ a1v, const float* __restrict__ a2v,
                      float* __restrict__ wa1, float* __restrict__ wa2,
                      float* __restrict__ ba) {
  const int k = threadIdx.x;
  if (k < 128) {
    float s1 = 0.f, s2 = 0.f;
    for (int g = 0; g < 128; ++g) {
      const float w = Ww[k * 128 + g];
      s1 = fmaf(w, a1v[g], s1);
      s2 = fmaf(w, a2v[g], s2);
    }
    wa1[k] = s1 * kLog2e;
    wa2[k] = s2 * kLog2e;
  }
  if (k == 128) {
    float s1 = 0.f, s2 = 0.f;
    for (int g = 0; g < 128; ++g) {
      s1 = fmaf(Wb[g], a1v[g], s1);
      s2 = fmaf(Wb[g], a2v[g], s2);
    }
    ba[0] = s1 * kLog2e;
    ba[1] = s2 * kLog2e;
  }
}

__global__ void prep2(const float* __restrict__ Ww, const int* __restrict__ adj,
                      const float* __restrict__ wa1, const float* __restrict__ wa2,
                      unsigned short* __restrict__ wf, unsigned int* __restrict__ adjp) {
  const int tid = blockIdx.x * 256 + threadIdx.x;
  if (tid < 18432) {
    // frag order: wf[g][kc][lane][j] = B[k = kc*32 + (lane>>4)*8 + j][col = g*16 + (lane&15)]
    const int j = tid & 7, l = (tid >> 3) & 63, kc = (tid >> 9) & 3, g = tid >> 11;
    const int k = kc * 32 + ((l >> 4) << 3) + j;
    const int c = l & 15;
    float x;
    if (g < 8) x = Ww[k * 128 + g * 16 + c];
    else       x = (c == 0) ? wa1[k] : (c == 1) ? wa2[k] : 0.f;
    wf[tid] = f2bf(x);
  }
  if (tid < 512) {
    const int row = tid >> 2, wd = tid & 3;
    const int* ap = adj + row * 128 + wd * 32;
    unsigned int bits = 0u;
#pragma unroll
    for (int b = 0; b < 32; ++b) bits |= (ap[b] != 0 ? (1u << b) : 0u);
    adjp[tid] = bits;
  }
}

// LDS: 32768 + 512 + 512 + 2048 + 33792 = 69632 B  -> 2 blocks/CU
struct SMem {
  unsigned short Whs[8][4][64][8];  // Wh in B-frag order
  float f1s[128];                   // log2 domain
  float f2s[128];
  unsigned int adjs[512];
  float stage[4][16][132];          // per-wave store stage (not aliased)
};

// Persistent 2-problem pipeline: loads for bs(i+1) fly under bs(i)'s compute.
__global__ __launch_bounds__(256, 2) void gat_fused2(
    const float* __restrict__ h,     // [BS][128][128]
    const float* __restrict__ Wb,    // [128]
    const float* __restrict__ abp,   // [1]
    const unsigned short* __restrict__ wf,
    const unsigned int* __restrict__ adjp,
    const float* __restrict__ ba,
    float* __restrict__ out,         // [BS][128][128]
    int BS) {
  __shared__ SMem sm;
  const int t    = threadIdx.x;
  const int lane = t & 63;
  const int w    = t >> 6;
  const int lr   = lane & 15;
  const int lg   = lane >> 4;
  const int R0   = w * 32;
  const float ab2 = abp[0] * kLog2e;
  const float ba1 = ba[0], ba2v = ba[1];

  float wbc[8];
#pragma unroll
  for (int g = 0; g < 8; ++g) wbc[g] = Wb[g * 16 + lr];

  *(uint2*)(sm.adjs + t * 2) = *(const uint2*)(adjp + t * 2);

  constexpr int NB = 2;
  const int bs0 = blockIdx.x * NB;

  // ---- prologue: issue h loads for bs0 ----
  f32x4 pre[16];
  {
    const float* hb = h + (size_t)bs0 * 16384;
#pragma unroll
    for (int rt = 0; rt < 2; ++rt)
#pragma unroll
      for (int kc = 0; kc < 4; ++kc) {
        const float* p = hb + (R0 + rt * 16 + lr) * 128 + kc * 32 + lg * 8;
        pre[(rt * 4 + kc) * 2]     = *(const f32x4*)p;
        pre[(rt * 4 + kc) * 2 + 1] = *(const f32x4*)(p + 4);
      }
  }

#pragma unroll
  for (int it = 0; it < NB; ++it) {
    const int bs = bs0 + it;
    if (bs >= BS) break;

    // ---- convert current pre -> A-frags ----
    bf16x8 ha[2][4];
#pragma unroll
    for (int rt = 0; rt < 2; ++rt)
#pragma unroll
      for (int kc = 0; kc < 4; ++kc) {
        const f32x4 v0 = pre[(rt * 4 + kc) * 2];
        const f32x4 v1 = pre[(rt * 4 + kc) * 2 + 1];
        union { bf16x8 v; unsigned int u[4]; } pk;
        pk.u[0] = f2bf2(v0[0], v0[1]);
        pk.u[1] = f2bf2(v0[2], v0[3]);
        pk.u[2] = f2bf2(v1[0], v1[1]);
        pk.u[3] = f2bf2(v1[2], v1[3]);
        ha[rt][kc] = pk.v;
      }

    // ---- issue next problem's loads (fly under all compute below) ----
    if (it + 1 < NB && bs + 1 < BS) {
      const float* hb = h + (size_t)(bs + 1) * 16384;
#pragma unroll
      for (int rt = 0; rt < 2; ++rt)
#pragma unroll
        for (int kc = 0; kc < 4; ++kc) {
          const float* p = hb + (R0 + rt * 16 + lr) * 128 + kc * 32 + lg * 8;
          pre[(rt * 4 + kc) * 2]     = *(const f32x4*)p;
          pre[(rt * 4 + kc) * 2 + 1] = *(const f32x4*)(p + 4);
        }
    }

    // ---- matmul1: [Wh | f1 f2] = bf16(h) @ bf16([W | wa1 wa2]) ----
    f32x4 acc[2][9];
#pragma unroll
    for (int rt = 0; rt < 2; ++rt)
#pragma unroll
      for (int g = 0; g < 9; ++g) acc[rt][g] = (f32x4){0.f, 0.f, 0.f, 0.f};

#pragma unroll
    for (int g = 0; g < 9; ++g)
#pragma unroll
      for (int kc = 0; kc < 4; ++kc) {
        const bf16x8 bh = *(const bf16x8*)(wf + ((g * 4 + kc) * 64 + lane) * 8);
        acc[0][g] = __builtin_amdgcn_mfma_f32_16x16x32_bf16(ha[0][kc], bh, acc[0][g], 0, 0, 0);
        acc[1][g] = __builtin_amdgcn_mfma_f32_16x16x32_bf16(ha[1][kc], bh, acc[1][g], 0, 0, 0);
      }

    // barrier A: all waves done reading f1s/f2s/Whs of previous iteration
    __syncthreads();

    // ---- bias + f1/f2 scatter + Wh -> LDS (B-frag order) ----
#pragma unroll
    for (int rt = 0; rt < 2; ++rt) {
#pragma unroll
      for (int r = 0; r < 4; ++r) {
        // C/D layout: row = R0 + rt*16 + lg*4 + r, col = g*16 + lr
#pragma unroll
        for (int g = 0; g < 8; ++g) acc[rt][g][r] += wbc[g];
        const int row = R0 + rt * 16 + lg * 4 + r;
        if (lr == 0)      sm.f1s[row] = acc[rt][8][r] + ba1;
        else if (lr == 1) sm.f2s[row] = acc[rt][8][r] + ba2v;
      }
#pragma unroll
      for (int g = 0; g < 8; ++g) {
        const unsigned int plo = f2bf2(acc[rt][g][0], acc[rt][g][1]);
        const unsigned int phi = f2bf2(acc[rt][g][2], acc[rt][g][3]);
        const int lp = (2 * rt + (lg >> 1)) * 16 + lr;
        const int jb = (lg & 1) * 4;
        *(uint2*)(&sm.Whs[g][w][lp][jb]) = make_uint2(plo, phi);
      }
    }
    __syncthreads();  // barrier B: Whs/f1/f2 visible

    // ---- P-build: single pass, log2 domain ----
    bf16x8 af[2][4];
    float s0 = 0.f, s1 = 0.f;
    const float f1i0 = sm.f1s[R0 + lr] + ab2;
    const float f1i1 = sm.f1s[R0 + 16 + lr] + ab2;
    const int rq0 = (R0 + lr) * 4, rq1 = (R0 + 16 + lr) * 4;
#pragma unroll
    for (int kc = 0; kc < 4; ++kc) {
      const f32x4 fv0 = *(const f32x4*)(&sm.f2s[kc * 32 + lg * 8]);
      const f32x4 fv1 = *(const f32x4*)(&sm.f2s[kc * 32 + lg * 8 + 4]);
      const unsigned int aw0 = sm.adjs[rq0 + kc];
      const unsigned int aw1 = sm.adjs[rq1 + kc];
      union { bf16x8 v; unsigned int u[4]; } pk0, pk1;
#pragma unroll
      for (int qq = 0; qq < 4; ++qq) {
        float e0[2], e1[2];
#pragma unroll
        for (int hh = 0; hh < 2; ++hh) {
          const int q = qq * 2 + hh;
          const float fj = (q < 4) ? fv0[q] : fv1[q - 4];
          const unsigned int bit = 1u << (lg * 8 + q);
          float x0 = f1i0 + fj;
          x0 = x0 >= 0.f ? x0 : kSlope * x0;
          x0 = (aw0 & bit) ? x0 : kNegInf;
          e0[hh] = exp2_hw(x0);
          float x1 = f1i1 + fj;
          x1 = x1 >= 0.f ? x1 : kSlope * x1;
          x1 = (aw1 & bit) ? x1 : kNegInf;
          e1[hh] = exp2_hw(x1);
        }
        const unsigned int u0 = f2bf2(e0[0], e0[1]);
        const unsigned int u1 = f2bf2(e1[0], e1[1]);
        pk0.u[qq] = u0;
        pk1.u[qq] = u1;
        s0 += __uint_as_float(u0 << 16) + __uint_as_float(u0 & 0xffff0000u);
        s1 += __uint_as_float(u1 << 16) + __uint_as_float(u1 & 0xffff0000u);
      }
      af[0][kc] = pk0.v;
      af[1][kc] = pk1.v;
    }
    s0 += __shfl_xor(s0, 16);
    s0 += __shfl_xor(s0, 32);
    s1 += __shfl_xor(s1, 16);
    s1 += __shfl_xor(s1, 32);
    float rs[2] = {s0, s1};

    // ---- matmul2: h'·l = P @ Wh ----
    f32x4 acc2[2][8];
#pragma unroll
    for (int rt = 0; rt < 2; ++rt)
#pragma unroll
      for (int g = 0; g < 8; ++g) acc2[rt][g] = (f32x4){0.f, 0.f, 0.f, 0.f};

#pragma unroll
    for (int g = 0; g < 8; ++g)
#pragma unroll
      for (int kc = 0; kc < 4; ++kc) {
        const bf16x8 bw = *(const bf16x8*)(&sm.Whs[g][kc][lane][0]);
        acc2[0][g] = __builtin_amdgcn_mfma_f32_16x16x32_bf16(af[0][kc], bw, acc2[0][g], 0, 0, 0);
        acc2[1][g] = __builtin_amdgcn_mfma_f32_16x16x32_bf16(af[1][kc], bw, acc2[1][g], 0, 0, 0);
      }

    // ---- normalize + elu + wave-private staged coalesced store ----
    float* oblk = out + (size_t)bs * 16384;
#pragma unroll
    for (int rt = 0; rt < 2; ++rt) {
      float inv[4];
#pragma unroll
      for (int r = 0; r < 4; ++r) {
        const float lsum = __shfl(rs[rt], (lane & 48) | (lg * 4 + r));
        inv[r] = __builtin_amdgcn_rcpf(lsum);
      }
#pragma unroll
      for (int r = 0; r < 4; ++r)
#pragma unroll
        for (int g = 0; g < 8; ++g) {
          float v = acc2[rt][g][r] * inv[r];
          v = v > 0.f ? v : __expf(v) - 1.0f;
          sm.stage[w][lg * 4 + r][g * 16 + lr] = v;
        }
      // wave-local RAW on stage: DS in-order per wave, compiler inserts lgkmcnt
#pragma unroll
      for (int sstep = 0; sstep < 8; ++sstep) {
        const int row16 = ((sstep & 1) << 3) + (lane >> 3);
        const int cd    = ((sstep >> 1) << 5) + ((lane & 7) << 2);
        f32x4 vv = *(const f32x4*)(&sm.stage[w][row16][cd]);
        *(f32x4*)(oblk + (size_t)(R0 + rt * 16 + row16) * 128 + cd) = vv;
      }
    }
  }
}

}  // namespace

extern "C" void kernel_launch(void* const* d_in, const int* in_sizes, int n_in,
                              void* d_out, int out_size, void* d_ws, size_t ws_size,
                              hipStream_t stream) {
  const float* h   = (const float*)d_in[0];
  const float* Ww  = (const float*)d_in[1];
  const float* Wb  = (const float*)d_in[2];
  const float* a1v = (const float*)d_in[3];
  const float* a2v = (const float*)d_in[4];
  const float* ab  = (const float*)d_in[5];
  const int*   adj = (const int*)d_in[6];
  float* out = (float*)d_out;

  unsigned short* wf   = (unsigned short*)d_ws;
  unsigned int*   adjp = (unsigned int*)((char*)d_ws + 36864);
  float*          wa1  = (float*)((char*)d_ws + 38912);
  float*          wa2  = (float*)((char*)d_ws + 39424);
  float*          ba   = (float*)((char*)d_ws + 39936);

  hipLaunchKernelGGL(prep1, dim3(1), dim3(256), 0, stream, Ww, Wb, a1v, a2v, wa1, wa2, ba);
  hipLaunchKernelGGL(prep2, dim3(72), dim3(256), 0, stream, Ww, adj, wa1, wa2, wf, adjp);

  const int BS = in_sizes[0] / 16384;  // 1024
  const int grid = (BS + 1) / 2;
  hipLaunchKernelGGL(gat_fused2, dim3(grid), dim3(256), 0, stream,
                     h, Wb, ab, wf, adjp, ba, out, BS);
}

// Round 9
// 48.590 us; speedup vs baseline: 1.1258x; 1.0646x over previous
//
#include <hip/hip_runtime.h>
#include <hip/hip_bf16.h>
#include <cmath>

namespace {

typedef __attribute__((ext_vector_type(8))) short bf16x8;
typedef __attribute__((ext_vector_type(4))) float f32x4;

constexpr float kNegInf = -1000000000.0f;
constexpr float kSlope  = 0.2f;
constexpr float kLog2e  = 1.44269504088896340736f;

__device__ __forceinline__ unsigned short f2bf(float x) {
  unsigned int u = __float_as_uint(x);
  u = (u + 0x7FFFu + ((u >> 16) & 1u)) >> 16;  // RNE
  return (unsigned short)u;
}
// packed pair via v_cvt_pk_bf16_f32
__device__ __forceinline__ unsigned int f2bf2(float a, float b) {
  __hip_bfloat162 t = __float22bfloat162_rn(float2{a, b});
  union { __hip_bfloat162 h; unsigned int u; } c;
  c.h = t;
  return c.u;
}
__device__ __forceinline__ float exp2_hw(float x) {
#if __has_builtin(__builtin_amdgcn_exp2f)
  return __builtin_amdgcn_exp2f(x);
#else
  float r;
  asm("v_exp_f32 %0, %1\n\ts_nop 1" : "=v"(r) : "v"(x));
  return r;
#endif
}

// ---------------- ws layout ----------------
// [0)      ushort wf[18432]   [W | wa1 wa2] B-frag order, bf16 (wa log2e-scaled)
// [36864)  uint   adjp[512]
// [38912)  float  ba[2]       {log2e*Wb.a1, log2e*Wb.a2}

__global__ void prep(const float* __restrict__ Ww, const float* __restrict__ Wb,
                     const float* __restrict__ a1v, const float* __restrict__ a2v,
                     const int* __restrict__ adj,
                     unsigned short* __restrict__ wf, unsigned int* __restrict__ adjp,
                     float* __restrict__ ba) {
  const int tid = blockIdx.x * 256 + threadIdx.x;  // grid 72*256 = 18432 exactly
  // frag order: wf[g][kc][lane][j] = B[k = kc*32 + (lane>>4)*8 + j][col = g*16 + (lane&15)]
  {
    const int j = tid & 7, l = (tid >> 3) & 63, kc = (tid >> 9) & 3, g = tid >> 11;
    const int k = kc * 32 + ((l >> 4) << 3) + j;
    const int c = l & 15;
    float x = 0.f;
    if (g < 8) {
      x = Ww[k * 128 + g * 16 + c];
    } else if (c < 2) {
      const float* av = (c == 0) ? a1v : a2v;
      float s = 0.f;
      for (int q = 0; q < 32; ++q) {
        f32x4 wv = *(const f32x4*)(Ww + k * 128 + q * 4);
        f32x4 aa = *(const f32x4*)(av + q * 4);
        s = fmaf(wv[0], aa[0], fmaf(wv[1], aa[1], fmaf(wv[2], aa[2], fmaf(wv[3], aa[3], s))));
      }
      x = s * kLog2e;  // wa1/wa2, pre-scaled for exp2 domain
    }
    wf[tid] = f2bf(x);
  }
  if (tid < 512) {
    const int row = tid >> 2, wd = tid & 3;
    const int* ap = adj + row * 128 + wd * 32;
    unsigned int bits = 0u;
#pragma unroll
    for (int b = 0; b < 32; ++b) bits |= (ap[b] != 0 ? (1u << b) : 0u);
    adjp[tid] = bits;
  }
  if (tid >= 18368) {  // last wave of last block: ba via butterfly
    const int l = tid - 18368;
    float p1 = Wb[l] * a1v[l] + Wb[l + 64] * a1v[l + 64];
    float p2 = Wb[l] * a2v[l] + Wb[l + 64] * a2v[l + 64];
#pragma unroll
    for (int m = 1; m < 64; m <<= 1) {
      p1 += __shfl_xor(p1, m);
      p2 += __shfl_xor(p2, m);
    }
    if (l == 0) {
      ba[0] = p1 * kLog2e;
      ba[1] = p2 * kLog2e;
    }
  }
}

// LDS: wfs 36864 + union 33792 + adjs 2048 = 72704 B -> 2 blocks/CU
struct SMem {
  unsigned short wfs[9][4][64][8];     // [W|wa] B-frags, staged once per block
  union {
    struct {
      unsigned short Whs[8][4][64][8]; // Wh in B-frag order (32768)
      float f1s[128];                  // log2 domain
      float f2s[128];
    } a;
    float stage[4][16][132];           // 33792 — aliases Whs+f1s+f2s
  } u;
  unsigned int adjs[512];
};

__global__ __launch_bounds__(256, 2) void gat_fused3(
    const float* __restrict__ h,     // [BS][128][128]
    const float* __restrict__ Wb,    // [128]
    const float* __restrict__ abp,   // [1]
    const unsigned short* __restrict__ wf,
    const unsigned int* __restrict__ adjp,
    const float* __restrict__ ba,
    float* __restrict__ out,         // [BS][128][128]
    int BS) {
  __shared__ SMem sm;
  const int t    = threadIdx.x;
  const int lane = t & 63;
  const int w    = t >> 6;
  const int lr   = lane & 15;
  const int lg   = lane >> 4;
  const int R0   = w * 32;
  const float ab2 = abp[0] * kLog2e;
  const float ba1 = ba[0], ba2v = ba[1];

  // vector loads issued at top (oldest in vmcnt FIFO — waits on them never drain h)
  float wbc[8];
#pragma unroll
  for (int g = 0; g < 8; ++g) wbc[g] = Wb[g * 16 + lr];

  constexpr int NB = 2;
  const int bs0 = blockIdx.x * NB;

  // ---- head: wf loads + adj load (L2, oldest) -> h0 loads (younger) -> ds_writes ----
  f32x4 wtmp[9];
  {
    const f32x4* wfg = (const f32x4*)wf;  // 2304 f32x4 total
#pragma unroll
    for (int p = 0; p < 9; ++p) wtmp[p] = wfg[p * 256 + t];
  }
  const uint2 adjv = *(const uint2*)(adjp + t * 2);

  f32x4 pre[16];
  {
    const float* hb = h + (size_t)bs0 * 16384;
#pragma unroll
    for (int rt = 0; rt < 2; ++rt)
#pragma unroll
      for (int kc = 0; kc < 4; ++kc) {
        const float* p = hb + (R0 + rt * 16 + lr) * 128 + kc * 32 + lg * 8;
        pre[(rt * 4 + kc) * 2]     = *(const f32x4*)p;
        pre[(rt * 4 + kc) * 2 + 1] = *(const f32x4*)(p + 4);
      }
  }

  {  // stage wf + adj to LDS (waits only their own loads: vmcnt(16) leaves h0 in flight)
    f32x4* wfl = (f32x4*)sm.wfs;
#pragma unroll
    for (int p = 0; p < 9; ++p) wfl[p * 256 + t] = wtmp[p];
    *(uint2*)(sm.adjs + t * 2) = adjv;
  }
  __syncthreads();

#pragma unroll
  for (int it = 0; it < NB; ++it) {
    const int bs = bs0 + it;
    if (bs >= BS) break;

    // ---- convert pre -> A-frags (waits h loads; they had the prior iter to drain) ----
    bf16x8 ha[2][4];
#pragma unroll
    for (int rt = 0; rt < 2; ++rt)
#pragma unroll
      for (int kc = 0; kc < 4; ++kc) {
        const f32x4 v0 = pre[(rt * 4 + kc) * 2];
        const f32x4 v1 = pre[(rt * 4 + kc) * 2 + 1];
        union { bf16x8 v; unsigned int u[4]; } pk;
        pk.u[0] = f2bf2(v0[0], v0[1]);
        pk.u[1] = f2bf2(v0[2], v0[3]);
        pk.u[2] = f2bf2(v1[0], v1[1]);
        pk.u[3] = f2bf2(v1[2], v1[3]);
        ha[rt][kc] = pk.v;
      }

    // ---- issue next problem's h loads NOW (only vmem in flight besides stores) ----
    if (it + 1 < NB && bs + 1 < BS) {
      const float* hb = h + (size_t)(bs + 1) * 16384;
#pragma unroll
      for (int rt = 0; rt < 2; ++rt)
#pragma unroll
        for (int kc = 0; kc < 4; ++kc) {
          const float* p = hb + (R0 + rt * 16 + lr) * 128 + kc * 32 + lg * 8;
          pre[(rt * 4 + kc) * 2]     = *(const f32x4*)p;
          pre[(rt * 4 + kc) * 2 + 1] = *(const f32x4*)(p + 4);
        }
      __builtin_amdgcn_sched_barrier(0);  // pin issue point (no sinking past compute)
    }

    // ---- matmul1: [Wh | f1 f2] = bf16(h) @ wfs   (B-frags from LDS) ----
    f32x4 acc[2][9];
#pragma unroll
    for (int rt = 0; rt < 2; ++rt)
#pragma unroll
      for (int g = 0; g < 9; ++g) acc[rt][g] = (f32x4){0.f, 0.f, 0.f, 0.f};

#pragma unroll
    for (int g = 0; g < 9; ++g)
#pragma unroll
      for (int kc = 0; kc < 4; ++kc) {
        const bf16x8 bh = *(const bf16x8*)(&sm.wfs[g][kc][lane][0]);
        acc[0][g] = __builtin_amdgcn_mfma_f32_16x16x32_bf16(ha[0][kc], bh, acc[0][g], 0, 0, 0);
        acc[1][g] = __builtin_amdgcn_mfma_f32_16x16x32_bf16(ha[1][kc], bh, acc[1][g], 0, 0, 0);
      }

    __syncthreads();  // A: all waves done with prev iter's stage reads (union safety)

    // ---- bias + f1/f2 scatter + Wh -> LDS (B-frag order) ----
#pragma unroll
    for (int rt = 0; rt < 2; ++rt) {
#pragma unroll
      for (int r = 0; r < 4; ++r) {
        // C/D layout: row = R0 + rt*16 + lg*4 + r, col = g*16 + lr
#pragma unroll
        for (int g = 0; g < 8; ++g) acc[rt][g][r] += wbc[g];
        const int row = R0 + rt * 16 + lg * 4 + r;
        if (lr == 0)      sm.u.a.f1s[row] = acc[rt][8][r] + ba1;
        else if (lr == 1) sm.u.a.f2s[row] = acc[rt][8][r] + ba2v;
      }
#pragma unroll
      for (int g = 0; g < 8; ++g) {
        const unsigned int plo = f2bf2(acc[rt][g][0], acc[rt][g][1]);
        const unsigned int phi = f2bf2(acc[rt][g][2], acc[rt][g][3]);
        const int lp = (2 * rt + (lg >> 1)) * 16 + lr;
        const int jb = (lg & 1) * 4;
        *(uint2*)(&sm.u.a.Whs[g][w][lp][jb]) = make_uint2(plo, phi);
      }
    }
    __syncthreads();  // B: Whs/f1/f2 visible

    // ---- P-build: single pass, log2 domain ----
    bf16x8 af[2][4];
    float s0 = 0.f, s1 = 0.f;
    const float f1i0 = sm.u.a.f1s[R0 + lr] + ab2;
    const float f1i1 = sm.u.a.f1s[R0 + 16 + lr] + ab2;
    const int rq0 = (R0 + lr) * 4, rq1 = (R0 + 16 + lr) * 4;
#pragma unroll
    for (int kc = 0; kc < 4; ++kc) {
      const f32x4 fv0 = *(const f32x4*)(&sm.u.a.f2s[kc * 32 + lg * 8]);
      const f32x4 fv1 = *(const f32x4*)(&sm.u.a.f2s[kc * 32 + lg * 8 + 4]);
      const unsigned int aw0 = sm.adjs[rq0 + kc];
      const unsigned int aw1 = sm.adjs[rq1 + kc];
      union { bf16x8 v; unsigned int u[4]; } pk0, pk1;
#pragma unroll
      for (int qq = 0; qq < 4; ++qq) {
        float e0[2], e1[2];
#pragma unroll
        for (int hh = 0; hh < 2; ++hh) {
          const int q = qq * 2 + hh;
          const float fj = (q < 4) ? fv0[q] : fv1[q - 4];
          const unsigned int bit = 1u << (lg * 8 + q);
          float x0 = f1i0 + fj;
          x0 = x0 >= 0.f ? x0 : kSlope * x0;
          x0 = (aw0 & bit) ? x0 : kNegInf;
          e0[hh] = exp2_hw(x0);
          float x1 = f1i1 + fj;
          x1 = x1 >= 0.f ? x1 : kSlope * x1;
          x1 = (aw1 & bit) ? x1 : kNegInf;
          e1[hh] = exp2_hw(x1);
        }
        const unsigned int u0 = f2bf2(e0[0], e0[1]);
        const unsigned int u1 = f2bf2(e1[0], e1[1]);
        pk0.u[qq] = u0;
        pk1.u[qq] = u1;
        s0 += __uint_as_float(u0 << 16) + __uint_as_float(u0 & 0xffff0000u);
        s1 += __uint_as_float(u1 << 16) + __uint_as_float(u1 & 0xffff0000u);
      }
      af[0][kc] = pk0.v;
      af[1][kc] = pk1.v;
    }
    s0 += __shfl_xor(s0, 16);
    s0 += __shfl_xor(s0, 32);
    s1 += __shfl_xor(s1, 16);
    s1 += __shfl_xor(s1, 32);
    float rs[2] = {s0, s1};

    // ---- matmul2: h'·l = P @ Wh ----
    f32x4 acc2[2][8];
#pragma unroll
    for (int rt = 0; rt < 2; ++rt)
#pragma unroll
      for (int g = 0; g < 8; ++g) acc2[rt][g] = (f32x4){0.f, 0.f, 0.f, 0.f};

#pragma unroll
    for (int g = 0; g < 8; ++g)
#pragma unroll
      for (int kc = 0; kc < 4; ++kc) {
        const bf16x8 bw = *(const bf16x8*)(&sm.u.a.Whs[g][kc][lane][0]);
        acc2[0][g] = __builtin_amdgcn_mfma_f32_16x16x32_bf16(af[0][kc], bw, acc2[0][g], 0, 0, 0);
        acc2[1][g] = __builtin_amdgcn_mfma_f32_16x16x32_bf16(af[1][kc], bw, acc2[1][g], 0, 0, 0);
      }
    __syncthreads();  // C: all Whs reads done before stage overwrites

    // ---- normalize + elu + wave-private staged coalesced store ----
    float* oblk = out + (size_t)bs * 16384;
#pragma unroll
    for (int rt = 0; rt < 2; ++rt) {
      float inv[4];
#pragma unroll
      for (int r = 0; r < 4; ++r) {
        const float lsum = __shfl(rs[rt], (lane & 48) | (lg * 4 + r));
        inv[r] = __builtin_amdgcn_rcpf(lsum);
      }
#pragma unroll
      for (int r = 0; r < 4; ++r)
#pragma unroll
        for (int g = 0; g < 8; ++g) {
          float v = acc2[rt][g][r] * inv[r];
          v = v > 0.f ? v : __expf(v) - 1.0f;
          sm.u.stage[w][lg * 4 + r][g * 16 + lr] = v;
        }
      // wave-local RAW on stage: DS in-order per wave
#pragma unroll
      for (int sstep = 0; sstep < 8; ++sstep) {
        const int row16 = ((sstep & 1) << 3) + (lane >> 3);
        const int cd    = ((sstep >> 1) << 5) + ((lane & 7) << 2);
        f32x4 vv = *(const f32x4*)(&sm.u.stage[w][row16][cd]);
        *(f32x4*)(oblk + (size_t)(R0 + rt * 16 + row16) * 128 + cd) = vv;
      }
    }
  }
}

}  // namespace

extern "C" void kernel_launch(void* const* d_in, const int* in_sizes, int n_in,
                              void* d_out, int out_size, void* d_ws, size_t ws_size,
                              hipStream_t stream) {
  const float* h   = (const float*)d_in[0];
  const float* Ww  = (const float*)d_in[1];
  const float* Wb  = (const float*)d_in[2];
  const float* a1v = (const float*)d_in[3];
  const float* a2v = (const float*)d_in[4];
  const float* ab  = (const float*)d_in[5];
  const int*   adj = (const int*)d_in[6];
  float* out = (float*)d_out;

  unsigned short* wf   = (unsigned short*)d_ws;
  unsigned int*   adjp = (unsigned int*)((char*)d_ws + 36864);
  float*          ba   = (float*)((char*)d_ws + 38912);

  hipLaunchKernelGGL(prep, dim3(72), dim3(256), 0, stream, Ww, Wb, a1v, a2v, adj, wf, adjp, ba);

  const int BS = in_sizes[0] / 16384;  // 1024
  const int grid = (BS + 1) / 2;
  hipLaunchKernelGGL(gat_fused3, dim3(grid), dim3(256), 0, stream,
                     h, Wb, ab, wf, adjp, ba, out, BS);
}